// Round 26
// baseline (121.966 us; speedup 1.0000x reference)
//
#include <hip/hip_runtime.h>
#include <hip/hip_bf16.h>
#include <cstdint>
#include <math.h>

#define NB   2
#define NS   2048
#define ND   1024
#define NH   16
#define NDK  64
#define N3D  3072

typedef __attribute__((ext_vector_type(8))) short short8;
typedef __attribute__((ext_vector_type(4))) float f32x4;

__device__ __forceinline__ unsigned short f2bf_u(float f) {
  __hip_bfloat16 h = __float2bfloat16(f);   // RNE
  return __builtin_bit_cast(unsigned short, h);
}
__device__ __forceinline__ float bfu2f(unsigned short u) {
  __hip_bfloat16 h = __builtin_bit_cast(__hip_bfloat16, u);
  return __bfloat162float(h);
}
__device__ __forceinline__ float bfr(float x) {
  return __bfloat162float(__float2bfloat16(x));
}

#define MFMA16(a, b, c) __builtin_amdgcn_mfma_f32_16x16x32_bf16((a), (b), (c), 0, 0, 0)
#define AS1 __attribute__((address_space(1)))
#define AS3 __attribute__((address_space(3)))

// ---------------- trig tables ----------------
__global__ void trig_tab(const int* __restrict__ pos, float* __restrict__ ctab,
                         float* __restrict__ stab) {
  const int idx = blockIdx.x * 256 + threadIdx.x;   // NB*NS*32
  const int d = idx & 31;
  const int s = (idx >> 5) & (NS - 1);
  const int b = idx >> 16;
  const float p   = (float)pos[b * NS + s];
  const float pw  = (float)pow(10000.0, (double)d / 32.0);
  const float inv = __fdiv_rn(1.0f, pw);
  const float ang = __fmul_rn(p, inv);
  ctab[idx] = (float)cos((double)ang);
  stab[idx] = (float)sin((double)ang);
}

// ---------------- f32 -> bf16 bulk convert ----------------
__global__ void cvt_bf16(const float* __restrict__ src, unsigned short* __restrict__ dst, int n4) {
  const int i = blockIdx.x * 256 + threadIdx.x;
  if (i >= n4) return;
  float4 v = reinterpret_cast<const float4*>(src)[i];
  ushort4 o;
  o.x = f2bf_u(v.x); o.y = f2bf_u(v.y); o.z = f2bf_u(v.z); o.w = f2bf_u(v.w);
  reinterpret_cast<ushort4*>(dst)[i] = o;
}

// ---------------- transpose + convert ----------------
__global__ void transpose_cvt(const float* __restrict__ src, unsigned short* __restrict__ dst,
                              int R, int srcStride) {
  __shared__ float tile[32][33];
  int c0 = blockIdx.x * 32, r0 = blockIdx.y * 32;
  int tx = threadIdx.x, ty = threadIdx.y;  // block (32,8)
  #pragma unroll
  for (int i = 0; i < 32; i += 8)
    tile[ty + i][tx] = src[(size_t)(r0 + ty + i) * srcStride + (c0 + tx)];
  __syncthreads();
  #pragma unroll
  for (int i = 0; i < 32; i += 8)
    dst[(size_t)(c0 + ty + i) * R + (r0 + tx)] = f2bf_u(tile[tx][ty + i]);
}

// ---------------- GEMM 128x128, BK=64, both operands bf16 via global_load_lds (m97 path).
// MODE 0: qkv fused epilogue (rope -> qc/kc, v -> vT). MODE 1: proj epilogue (f32 out). ----------------
template<int MODE>
__global__ __launch_bounds__(256, 2)
void gemm2(const unsigned short* __restrict__ A16, const unsigned short* __restrict__ BT, int K,
           const float* __restrict__ bias, const float* __restrict__ ctab,
           const float* __restrict__ stab, unsigned short* __restrict__ qcb,
           unsigned short* __restrict__ kcb, unsigned short* __restrict__ vT,
           float* __restrict__ fout) {
  __shared__ unsigned short As[128 * 64];
  __shared__ unsigned short Bs[128 * 64];
  const int tid = threadIdx.x;
  const int wave = tid >> 6;
  const int lane = tid & 63;
  const int m0 = blockIdx.x * 128;
  const int n0 = blockIdx.y * 128;
  const int wr = wave >> 1, wc = wave & 1;

  f32x4 acc[4][4] = {};

  for (int kt = 0; kt < K; kt += 64) {
    __syncthreads();
    #pragma unroll
    for (int j = 0; j < 4; ++j) {
      const int c = (wave * 4 + j) * 64 + lane;
      const int row = c >> 3, col8 = c & 7;
      __builtin_amdgcn_global_load_lds(
          (const AS1 void*)(A16 + (size_t)(m0 + row) * K + kt + col8 * 8),
          (AS3 void*)(As + (wave * 4 + j) * 512), 16, 0, 0);
    }
    #pragma unroll
    for (int j = 0; j < 4; ++j) {
      const int c = (wave * 4 + j) * 64 + lane;
      const int row = c >> 3, col8 = c & 7;
      __builtin_amdgcn_global_load_lds(
          (const AS1 void*)(BT + (size_t)(n0 + row) * K + kt + col8 * 8),
          (AS3 void*)(Bs + (wave * 4 + j) * 512), 16, 0, 0);
    }
    asm volatile("s_waitcnt vmcnt(0)" ::: "memory");
    __syncthreads();

    #pragma unroll
    for (int kc = 0; kc < 2; ++kc) {
      short8 af[4], bfrg[4];
      const int gw = kc * 4 + (lane >> 4);
      #pragma unroll
      for (int m = 0; m < 4; ++m) {
        const int row = wr * 64 + m * 16 + (lane & 15);
        af[m] = *reinterpret_cast<const short8*>(As + row * 64 + gw * 8);
      }
      #pragma unroll
      for (int n = 0; n < 4; ++n) {
        const int row = wc * 64 + n * 16 + (lane & 15);
        bfrg[n] = *reinterpret_cast<const short8*>(Bs + row * 64 + gw * 8);
      }
      #pragma unroll
      for (int m = 0; m < 4; ++m)
        #pragma unroll
        for (int n = 0; n < 4; ++n)
          acc[m][n] = MFMA16(af[m], bfrg[n], acc[m][n]);
    }
  }

  const int colbase = n0 + wc * 64;
  const int rowbase = m0 + wr * 64;

  if (MODE == 1) {
    #pragma unroll
    for (int n = 0; n < 4; ++n) {
      const int col = colbase + n * 16 + (lane & 15);
      const float bv = bfr(bias[col]);
      #pragma unroll
      for (int m = 0; m < 4; ++m)
        #pragma unroll
        for (int jj = 0; jj < 4; ++jj) {
          const int row = rowbase + m * 16 + (lane >> 4) * 4 + jj;
          float r = bfr(acc[m][n][jj]);   // bf16 dot result (XLA semantics)
          r = bfr(r + bv);                // bf16 bias add
          fout[(size_t)row * ND + col] = r;
        }
    }
    return;
  }

  const int sec = colbase >> 10;          // 0=q 1=k 2=v (uniform per wave)
  if (sec < 2) {
    unsigned short* dst = (sec == 0) ? qcb : kcb;
    #pragma unroll
    for (int n = 0; n < 2; ++n) {
      const int col1 = colbase + n * 16 + (lane & 15);   // d in 0..31
      const int col2 = col1 + 32;
      const float bv1 = bfr(bias[col1]);
      const float bv2 = bfr(bias[col2]);
      const int h = (col1 & 1023) >> 6;
      const int d = col1 & 63;
      #pragma unroll
      for (int m = 0; m < 4; ++m)
        #pragma unroll
        for (int jj = 0; jj < 4; ++jj) {
          const int row = rowbase + m * 16 + (lane >> 4) * 4 + jj;
          const int b = row >> 11, s = row & (NS - 1);
          const float x1 = bfr(bfr(acc[m][n][jj])     + bv1);
          const float x2 = bfr(bfr(acc[m][n + 2][jj]) + bv2);
          const float cs = ctab[(size_t)(b * NS + s) * 32 + d];
          const float sn = stab[(size_t)(b * NS + s) * 32 + d];
          const size_t base = ((size_t)(b * NH + h) * NS + s) * NDK + d;
          dst[base]      = f2bf_u(__fadd_rn(__fmul_rn(x1, cs), __fmul_rn(-x2, sn)));
          dst[base + 32] = f2bf_u(__fadd_rn(__fmul_rn(x2, cs), __fmul_rn(x1, sn)));
        }
    }
  } else {
    #pragma unroll
    for (int n = 0; n < 4; ++n) {
      const int col = colbase + n * 16 + (lane & 15);
      const int lc = col & 1023;
      const int h = lc >> 6, dk = lc & 63;
      const float bv = bfr(bias[col]);
      #pragma unroll
      for (int m = 0; m < 4; ++m)
        #pragma unroll
        for (int jj = 0; jj < 4; ++jj) {
          const int row = rowbase + m * 16 + (lane >> 4) * 4 + jj;
          const int b = row >> 11, s = row & (NS - 1);
          float r = bfr(acc[m][n][jj]);
          r = bfr(r + bv);
          vT[((size_t)(b * NH + h) * NDK + dk) * NS + s] = f2bf_u(r);
        }
    }
  }
}

// ---------------- pipelined fixed-shift flash: PV(t-1) overlaps S(t)/exp(t) ----------------
// Paired q-tiles (31-i4, i4): 33 iterations/block, grid 512. K ring depth 2, V ring depth 3,
// P double-buffered per wave. m == 8 fixed shift; l via ones-MFMA.
__global__ __launch_bounds__(256, 2)
void flash7(const unsigned short* __restrict__ qc, const unsigned short* __restrict__ kc,
            const unsigned short* __restrict__ vT, unsigned short* __restrict__ aob) {
  __shared__ unsigned short Ks[2][64 * 64];
  __shared__ unsigned short Vs[3][64 * 64];
  __shared__ unsigned short Pl[4][2][16 * 64];
  const int tid = threadIdx.x;
  const int wave = tid >> 6, lane = tid & 63;
  const int flat = blockIdx.x;            // 0..511
  const int xcd = flat & 7;
  const int idx = flat >> 3;              // 0..63
  const int hg = idx >> 4;                // 0..3
  const int i4 = idx & 15;                // 0..15
  const int bh = xcd * 4 + hg;
  const int b = bh >> 4, h = bh & 15;
  const unsigned short* Qh = qc + (size_t)bh * NS * NDK;
  const unsigned short* Kh = kc + (size_t)bh * NS * NDK;
  const unsigned short* Vh = vT + (size_t)bh * NDK * NS;
  const short8 vone = {0x3F80, 0x3F80, 0x3F80, 0x3F80, 0x3F80, 0x3F80, 0x3F80, 0x3F80}; // bf16 1.0

#define STAGE_K(KV0, BUF)                                                          \
  {                                                                                \
    _Pragma("unroll")                                                              \
    for (int j = 0; j < 2; ++j) {                                                  \
      const int c = (j * 4 + wave) * 64 + lane;                                    \
      const int row = c >> 3, ch = c & 7;                                          \
      __builtin_amdgcn_global_load_lds(                                            \
          (const AS1 void*)(Kh + (size_t)((KV0) + row) * NDK + ((ch ^ (row & 7)) * 8)), \
          (AS3 void*)((BUF) + (j * 4 + wave) * 512), 16, 0, 0);                    \
    }                                                                              \
  }
#define STAGE_V(KV0, BUF)                                                          \
  {                                                                                \
    _Pragma("unroll")                                                              \
    for (int j = 0; j < 2; ++j) {                                                  \
      const int c = (j * 4 + wave) * 64 + lane;                                    \
      const int row = c >> 3, ch = c & 7;                                          \
      __builtin_amdgcn_global_load_lds(                                            \
          (const AS1 void*)(Vh + (size_t)row * NS + (KV0) + ((ch ^ (row & 7)) * 8)), \
          (AS3 void*)((BUF) + (j * 4 + wave) * 512), 16, 0, 0);                    \
    }                                                                              \
  }

  // PV + l for one tile from Vs[vb] using Pl[wave][ppb]
#define PV_TILE(VB, PPB)                                                           \
  {                                                                                \
    short8 pa[2];                                                                  \
    _Pragma("unroll")                                                              \
    for (int kk = 0; kk < 2; ++kk) {                                               \
      const int prow = lane & 15;                                                  \
      const int gw = kk * 4 + (lane >> 4);                                         \
      pa[kk] = *reinterpret_cast<const short8*>(Pl[wave][PPB] + prow * 64 +        \
                                                ((gw ^ (prow & 7)) * 8));          \
    }                                                                              \
    _Pragma("unroll")                                                              \
    for (int n2 = 0; n2 < 4; ++n2) {                                               \
      const int dk = n2 * 16 + (lane & 15);                                        \
      _Pragma("unroll")                                                            \
      for (int kk = 0; kk < 2; ++kk) {                                             \
        const int gw = kk * 4 + (lane >> 4);                                       \
        short8 bv = *reinterpret_cast<const short8*>(Vs[VB] + dk * 64 +            \
                                                     ((gw ^ (dk & 7)) * 8));       \
        oacc[n2] = MFMA16(pa[kk], bv, oacc[n2]);                                   \
      }                                                                            \
    }                                                                              \
    _Pragma("unroll")                                                              \
    for (int kk = 0; kk < 2; ++kk)                                                 \
      lacc = MFMA16(pa[kk], vone, lacc);                                           \
  }

  for (int qi = 0; qi < 2; ++qi) {
    const int qt = (qi == 0) ? (31 - i4) : i4;   // big tile first
    const int qw = qt * 64 + wave * 16;

    short8 aq[2];
    {
      const int qrow = qw + (lane & 15);
      #pragma unroll
      for (int kk = 0; kk < 2; ++kk)
        aq[kk] = *reinterpret_cast<const short8*>(Qh + (size_t)qrow * NDK + kk * 32 + (lane >> 4) * 8);
    }

    const int ntiles = qt + 1;
    STAGE_K(0, Ks[0]);
    STAGE_V(0, Vs[0]);
    asm volatile("s_waitcnt vmcnt(0)" ::: "memory");
    __syncthreads();

    f32x4 oacc[4] = {};
    f32x4 lacc = {};
    int pb = 0;
    int vprev = 2, vcurr = 0, vnext = 1;   // V ring indices: (t-1)%3, t%3, (t+1)%3

    for (int t = 0; t < ntiles; ++t) {
      // ---- PV for tile t-1 (operands consumed before staging below) ----
      if (t > 0) PV_TILE(vprev, pb ^ 1);

      // ---- prefetch tile t+1 (K 2-ring, V 3-ring: targets unread this window) ----
      if (t + 1 < ntiles) {
        STAGE_K(t * 64 + 64, Ks[(t + 1) & 1]);
        STAGE_V(t * 64 + 64, Vs[vnext]);
      }

      // ---- S(t) from Ks[t&1] ----
      f32x4 sacc[4];
      #pragma unroll
      for (int n = 0; n < 4; ++n) {
        const int krow = n * 16 + (lane & 15);
        f32x4 z = {};
        #pragma unroll
        for (int kk = 0; kk < 2; ++kk) {
          const int gw = kk * 4 + (lane >> 4);
          short8 bk = *reinterpret_cast<const short8*>(Ks[t & 1] + krow * 64 + ((gw ^ (krow & 7)) * 8));
          z = MFMA16(aq[kk], bk, z);
        }
        sacc[n] = z;
      }
      const bool diag = (t == qt);
      const int kv0 = t * 64;
      // e = exp(s*0.125 - 8); write bf16(e) to wave-private Pl[pb] (swizzled)
      #pragma unroll
      for (int n = 0; n < 4; ++n)
        #pragma unroll
        for (int jj = 0; jj < 4; ++jj) {
          float sv = sacc[n][jj] * 0.125f - 8.0f;
          if (diag) {
            const int col = kv0 + n * 16 + (lane & 15);
            const int row = qw + (lane >> 4) * 4 + jj;
            if (col > row) sv = -1e30f;
          }
          const float e = __expf(sv);
          const int prow = (lane >> 4) * 4 + jj;
          const int pcol = n * 16 + (lane & 15);
          const int chunk = pcol >> 3;
          Pl[wave][pb][prow * 64 + (chunk ^ (prow & 7)) * 8 + (pcol & 7)] = f2bf_u(e);
        }

      asm volatile("s_waitcnt vmcnt(0)" ::: "memory");   // prefetch landed
      __syncthreads();                                   // window boundary
      pb ^= 1;
      vprev = vcurr; vcurr = vnext; vnext = (vnext == 2) ? 0 : vnext + 1;
    }

    // ---- epilogue: PV for the last tile ----
    PV_TILE(vprev, pb ^ 1);

    #pragma unroll
    for (int n2 = 0; n2 < 4; ++n2)
      #pragma unroll
      for (int jj = 0; jj < 4; ++jj) {
        const int row = qw + (lane >> 4) * 4 + jj;
        aob[(size_t)(b * NS + row) * ND + h * NDK + n2 * 16 + (lane & 15)] =
            f2bf_u(oacc[n2][jj] / lacc[jj]);
      }

    __syncthreads();   // all waves done with Vs before next qi's staging
  }
#undef STAGE_K
#undef STAGE_V
#undef PV_TILE
}

// ---------------- launch ----------------
extern "C" void kernel_launch(void* const* d_in, const int* in_sizes, int n_in,
                              void* d_out, int out_size, void* d_ws, size_t ws_size,
                              hipStream_t stream) {
  const float* hs     = (const float*)d_in[0];
  const int*   pos    = (const int*)d_in[1];
  const float* w_attn = (const float*)d_in[2];
  const float* b_attn = (const float*)d_in[3];
  const float* w_proj = (const float*)d_in[4];
  const float* b_proj = (const float*)d_in[5];
  float* out = (float*)d_out;

  char* ws = (char*)d_ws;
  unsigned short* qc     = (unsigned short*)(ws);                  //  0..8 MB  [bh][s][64]
  unsigned short* kcb    = (unsigned short*)(ws + (8ull  << 20));  //  8..16 MB [bh][s][64]
  unsigned short* vT     = (unsigned short*)(ws + (16ull << 20));  // 16..24 MB [bh][dk][s]
  unsigned short* wqkvT  = (unsigned short*)(ws + (24ull << 20));  // 24..30 MB (dead after gemm0)
  unsigned short* aob    = (unsigned short*)(ws + (24ull << 20));  // 24..32 MB (overlays wqkvT)
  unsigned short* wprojT = (unsigned short*)(ws + (32ull << 20));  // 32..34 MB
  float*          ctab   = (float*)(ws + (34ull << 20));           // 0.5 MB
  float*          stab   = (float*)(ws + (34ull << 20) + (512ull << 10));

  // hs in bf16, staged in d_out (8 MB of 16 MB; proj fully overwrites d_out at the end)
  unsigned short* hsb = (unsigned short*)d_out;

  trig_tab<<<(NB * NS * 32) / 256, 256, 0, stream>>>(pos, ctab, stab);
  cvt_bf16<<<(NB * NS * ND / 4 + 255) / 256, 256, 0, stream>>>(hs, hsb, NB * NS * ND / 4);
  transpose_cvt<<<dim3(96, 32), dim3(32, 8), 0, stream>>>(w_attn, wqkvT, ND, N3D);
  gemm2<0><<<dim3(32, 24), 256, 0, stream>>>(hsb, wqkvT, ND, b_attn, ctab, stab,
                                             qc, kcb, vT, nullptr);
  flash7<<<512, 256, 0, stream>>>(qc, kcb, vT, aob);
  transpose_cvt<<<dim3(32, 32), dim3(32, 8), 0, stream>>>(w_proj, wprojT, ND, ND);
  gemm2<1><<<dim3(32, 8), 256, 0, stream>>>(aob, wprojT, ND, b_proj, nullptr, nullptr,
                                            nullptr, nullptr, nullptr, out);
}